// Round 3
// baseline (196.764 us; speedup 1.0000x reference)
//
#include <hip/hip_runtime.h>
#include <cstdint>
#include <cstddef>

// ---------------------------------------------------------------------------
// SOMFNN forward, 4 dispatches:
//   0. memset    : zero the atomic-accumulator region (~196 KB)
//   1. f2b_all   : convert x/W0/W1 to bf16; SENx + colsum bins; last block
//                  (fence-free done-counter) computes stau0
//   2. gemm L0   : fused Gram(dens,S0,e0,diag0)+sigmoid(hb,SENh,colsumH).
//   3. gemm L1   : 192 gemm blocks (Gram+sigmoid->out) + ONE tail-0 block
//                  (raw bx==24,by==0) computing stau1 then decide0+lamb0;
//                  last gemm block (done-counter) runs decide1+lamb1.
// R12: R11 proved the 128^2 kernel sits exactly on the staging-BW roofline
// (400MB staged @7.7TB/s = 52us; 64 FLOP/staged-byte * 7.7 = 496TF = measured).
// => raise intensity + locality, not pipelining:
//   (a) 256x128 tiles (87 FLOP/byte; L0 staged 512->384MB, L1 400->288MB).
//       8 waves = 4m x 2n, each owns 64x64; NO kg split -> epilogue is
//       direct (no LDS merge). LDS 2x48KB distinct-object double buffer
//       (R11 structure: static disjoint => no alias-forced vmcnt(0)).
//   (b) XCD-chunked swizzle: remap linear block id so each XCD owns one
//       256-row m-panel (L2-resident) swept over all n-tiles. L1's 8
//       special bx==24 blocks land one per XCD (js = 3*(xcd+1)).
// Buffer rotation: Dens1 overwrites the dead xb+wb0 region (w+0) so Dens0
// (w+28MB) stays intact for the concurrent decide0.
// Coherence: same-dispatch cross-block data only via device-scope atomics
// (fence-free done-counter: __syncthreads drains vmcnt(0) first); plain
// Dens reads only cross-dispatch or behind the straggler fence.
// Semantics (exact vs reference): stau=base/2 scalar (SENc==cn2); prototypes
// never updated => distances from Gram; e_i=0 => definitively NEW;
// stragglers resolved sequentially (T=0 for this data); lamb =
// dens(n,assigned)/(S[n] - reassigned densities).
// ---------------------------------------------------------------------------

#define DELTA_F 0.13533528323661270f  // float(exp(-2))
#define MBYTE (1u << 20)

typedef __bf16 bf16;
typedef bf16 bf16x8 __attribute__((ext_vector_type(8)));
typedef bf16 bf16x4 __attribute__((ext_vector_type(4)));
typedef float f32x4 __attribute__((ext_vector_type(4)));

typedef __attribute__((address_space(1))) void as1_void;
typedef __attribute__((address_space(3))) void as3_void;

__device__ __forceinline__ void gload16(const bf16* g, bf16* l) {
  __builtin_amdgcn_global_load_lds((as1_void*)g, (as3_void*)l, 16, 0, 0);
}

__device__ __forceinline__ float wave_reduce(float s) {
  for (int o = 32; o > 0; o >>= 1) s += __shfl_down(s, o, 64);
  return s;
}

// ---- shared decide+lamb tail. SAME=true: data written by THIS dispatch
// (atomic reads; fence only on straggler path). SAME=false: previous
// dispatch (plain reads). smem needs >= 24584 bytes. ----
template <bool SAME>
__device__ void run_decide_lamb(char* smem, int* e, float* Dens, float* S,
                                float* diagD, float* lambOut) {
  char* s_flag = smem;                    // 2048
  short* s_as = (short*)(smem + 2048);    // 4096
  short* s_list = (short*)(smem + 6144);  // 4096
  short* s_re = (short*)(smem + 10240);   // 4096
  int* scan_ = (int*)(smem + 14336);      // 2048
  float* rbest = (float*)(smem + 16384);  // 2048
  int* rbj = (int*)(smem + 18432);        // 2048
  int* sT = (int*)(smem + 24576);
  int* sReN = (int*)(smem + 24580);
  const int tid = threadIdx.x;
  int cntl = 0;
#pragma unroll
  for (int k = 0; k < 4; ++k) {
    const int i = tid * 4 + k;
    const int ei = SAME ? atomicOr(e + i, 0) : e[i];
    s_flag[i] = (ei == 0);
    if (ei == 0) s_as[i] = (short)i;
    cntl += (ei != 0);
  }
  scan_[tid] = cntl;
  if (tid == 0) sReN[0] = 0;
  __syncthreads();
  for (int off = 1; off < 512; off <<= 1) {
    const int v = scan_[tid];
    const int add = (tid >= off) ? scan_[tid - off] : 0;
    __syncthreads();
    scan_[tid] = v + add;
    __syncthreads();
  }
  int pos = scan_[tid] - cntl;
#pragma unroll
  for (int k = 0; k < 4; ++k) {
    const int i = tid * 4 + k;
    if (!s_flag[i]) s_list[pos++] = (short)i;
  }
  if (tid == 511) sT[0] = scan_[511];
  __syncthreads();
  const int T = sT[0];
  if (SAME && T > 0) __threadfence();  // straggler path only (rare)
  for (int t = 0; t < T; ++t) {
    const int i = s_list[t];
    const float* di = Dens + (size_t)i * 2048;
    float best = -1.0f;
    int bestj = 0x7fffffff;
    for (int j = tid; j < i; j += 512) {
      if (s_flag[j]) {
        const float d = di[j];
        if (d > best || (d == best && j < bestj)) { best = d; bestj = j; }
      }
    }
    rbest[tid] = best; rbj[tid] = bestj;
    __syncthreads();
    if (tid == 0) {
      float b = -1.0f;
      int bj = 0x7fffffff;
      for (int k = 0; k < 512; ++k)
        if (rbest[k] > b || (rbest[k] == b && rbj[k] < bj)) { b = rbest[k]; bj = rbj[k]; }
      if (b < DELTA_F) { s_flag[i] = 1; s_as[i] = (short)i; }
      else { s_as[i] = (short)bj; s_re[sReN[0]++] = (short)i; }
    }
    __syncthreads();
  }
  const int reN = sReN[0];
#pragma unroll
  for (int k = 0; k < 4; ++k) {
    const int n = k * 512 + tid;
    const int aa = s_as[n];
    const float num = (aa == n)
        ? (SAME ? atomicAdd(diagD + n, 0.f) : diagD[n])
        : Dens[(size_t)n * 2048 + aa];
    float denom = SAME ? atomicAdd(S + n, 0.f) : S[n];
    for (int t = 0; t < reN; ++t) denom -= Dens[(size_t)n * 2048 + s_re[t]];
    lambOut[n] = num / denom;
  }
}

// ------------------------------- GEMM --------------------------------------
// C[2048, *] = A[2048,2048] * Bcat^T, 256x128 tiles, 8 waves = 4m x 2n,
// BK=64, XOR-swizzled LDS (swizzle on global source address).
// 2-phase prefetch: TWO distinct 48KB __shared__ buffers (A 32KB + B 16KB),
// K-loop unrolled x2 with static buffer selection, one barrier per K-step.
template <bool IS_L0>
__global__ __launch_bounds__(512, 2) void gemm_fused(
    const bf16* __restrict__ A, float* __restrict__ Dens,
    bf16* __restrict__ Hb, float* __restrict__ Fo,
    const float* __restrict__ bias, const float* __restrict__ SENin,
    const float* __restrict__ ninv_p, float* __restrict__ S,
    int* __restrict__ e, float* __restrict__ SENhOut,
    float* __restrict__ colsumH, float* __restrict__ diagD,
    int* __restrict__ cnt, int nblocks, float* __restrict__ lambOut,
    // L1-only (concurrent layer-0 tail):
    int* __restrict__ flagN, const float* __restrict__ SENh_r,
    const float* __restrict__ colsumH_r, int* __restrict__ e0,
    float* __restrict__ S0, float* __restrict__ diag0,
    float* __restrict__ Dens0, float* __restrict__ lamb0) {
  __shared__ __align__(16) char smemA[49152];
  __shared__ __align__(16) char smemB[49152];
  __shared__ int s_last;
  const int tid = threadIdx.x;

  // ---------------- L1 tail-0 block: stau1 + decide0 + lamb0 ---------------
  // (raw blockIdx: specials excluded from the swizzle domain)
  if (!IS_L0 && blockIdx.x == 24) {
    if (blockIdx.y != 0) return;
    float* r1 = (float*)(smemA + 20480);
    float* r2 = (float*)(smemA + 22528);
    float ssen = 0.f, sg2 = 0.f;
    for (int i = tid; i < 2048; i += 512) ssen += SENh_r[i];
    for (int c = tid; c < 2048; c += 512) {
      const float gm = colsumH_r[c] * (1.f / 2048.f);
      sg2 += gm * gm;
    }
    r1[tid] = ssen; r2[tid] = sg2;
    __syncthreads();
    for (int s = 256; s; s >>= 1) {
      if (tid < s) { r1[tid] += r1[tid + s]; r2[tid] += r2[tid + s]; }
      __syncthreads();
    }
    if (tid == 0) {
      const float stau = 0.5f * (r1[0] * (1.f / 2048.f) - r2[0]);
      atomicExch(flagN, __float_as_int(-1.f / stau));  // value IS ninv1
    }
    __syncthreads();
    run_decide_lamb<false>(smemA, e0, Dens0, S0, diag0, lamb0);
    return;
  }

  // ---- XCD-chunked tile mapping: by' = lid&7 (one m-panel per XCD) ----
  int bx, by;
  if (IS_L0) {
    const int lid = blockIdx.x + (blockIdx.y << 5);  // grid (32,8)
    by = lid & 7; bx = lid >> 3;                     // bx 0..31
  } else {
    const int lid = blockIdx.x + blockIdx.y * 25;    // grid (25,8)
    const int xcd = lid & 7, j = lid >> 3;           // j 0..24
    by = xcd; bx = j - (j > 3 * (xcd + 1));          // skip special slot
  }
  const int m0 = by * 256, n0 = bx * 128;

  const int wave = tid >> 6, lane = tid & 63;
  const int quad = lane >> 4, l16 = lane & 15;
  const int wm = wave >> 1, wn = wave & 1;           // 4m x 2n
  const bool isGram = (n0 < 2048);
  const int sr8 = lane >> 3, slot = lane & 7;
  const int gk = (slot ^ sr8) * 8;  // swizzled global k-element offset
  const bf16* aSrc = A + (size_t)(m0 + wave * 32 + sr8) * 2048 + gk;
  const bf16* bSrc = A + (size_t)(n0 + wave * 16 + sr8) * 2048 + gk;
  char* const aDst0 = smemA + wave * 4096;
  char* const bDst0 = smemA + 32768 + wave * 2048;
  char* const aDst1 = smemB + wave * 4096;
  char* const bDst1 = smemB + 32768 + wave * 2048;
  const int aB = (wm * 64 + l16) * 128;
  const int bB = 32768 + (wn * 64 + l16) * 128;

#define STAGE(aD, bD, k)                                    \
  do {                                                      \
    gload16(aSrc + (k), (bf16*)(aD));                       \
    gload16(aSrc + 8 * 2048 + (k), (bf16*)((aD) + 1024));   \
    gload16(aSrc + 16 * 2048 + (k), (bf16*)((aD) + 2048));  \
    gload16(aSrc + 24 * 2048 + (k), (bf16*)((aD) + 3072));  \
    gload16(bSrc + (k), (bf16*)(bD));                       \
    gload16(bSrc + 8 * 2048 + (k), (bf16*)((bD) + 1024));   \
  } while (0)

#define COMPUTE(sm)                                                          \
  do {                                                                       \
    _Pragma("unroll") for (int ks = 0; ks < 2; ++ks) {                       \
      bf16x8 af[4], bfr[4];                                                  \
      const int sw = ((ks * 4 + quad) ^ (l16 & 7)) * 16;                     \
      _Pragma("unroll") for (int i = 0; i < 4; ++i)                          \
          af[i] = *(const bf16x8*)((sm) + aB + i * 2048 + sw);               \
      _Pragma("unroll") for (int j = 0; j < 4; ++j)                          \
          bfr[j] = *(const bf16x8*)((sm) + bB + j * 2048 + sw);              \
      _Pragma("unroll") for (int i = 0; i < 4; ++i)                          \
          _Pragma("unroll") for (int j = 0; j < 4; ++j) acc[i][j] =          \
              __builtin_amdgcn_mfma_f32_16x16x32_bf16(af[i], bfr[j],         \
                                                      acc[i][j], 0, 0, 0);   \
    }                                                                        \
  } while (0)

  f32x4 acc[4][4] = {};
  STAGE(aDst0, bDst0, 0);  // prologue: k=0 into buffer A
  for (int k0 = 0; k0 < 2048; k0 += 128) {
    __syncthreads();                      // bufA staged / prev B reads done
    STAGE(aDst1, bDst1, k0 + 64);         // k0+64 <= 1984 always valid
    COMPUTE(smemA);
    __syncthreads();                      // bufB staged / A reads done
    if (k0 + 128 < 2048) STAGE(aDst0, bDst0, k0 + 128);
    COMPUTE(smemB);
  }
#undef STAGE
#undef COMPUTE

  // ninv: L0 = plain read (prev dispatch); L1 = spin on flag (value = ninv1,
  // published ~3us into this dispatch -- epilogue is far later, 0 spins).
  float ninv = 0.f;
  if (isGram) {
    if (IS_L0) ninv = ninv_p[0];
    else {
      int fi;
      while ((fi = atomicOr(flagN, 0)) == 0) {}
      ninv = __int_as_float(fi);
    }
  }

  // epilogue: no kg merge -- every wave writes its own 64x64 sub-tile
  float colp[4] = {0.f, 0.f, 0.f, 0.f};
#pragma unroll
  for (int i = 0; i < 4; ++i) {
    const int rbase = m0 + wm * 64 + i * 16 + quad * 4;
    if (isGram) {
      const f32x4 si4 = *(const f32x4*)(SENin + rbase);
      float rp[4] = {0.f, 0.f, 0.f, 0.f};
      int er = 0;
#pragma unroll
      for (int j = 0; j < 4; ++j) {
        const f32x4 v = acc[i][j];
        const int col = n0 + wn * 64 + j * 16 + l16;
        const float sj = SENin[col];
#pragma unroll
        for (int r = 0; r < 4; ++r) {
          const float dens = __expf((si4[r] + sj - 2.0f * v[r]) * ninv);
          Dens[(size_t)(rbase + r) * 2048 + col] = dens;
          rp[r] += dens;
          if (col < rbase + r && dens >= DELTA_F) er |= (1 << r);
          if (col == rbase + r) atomicExch(diagD + col, dens);
        }
      }
#pragma unroll
      for (int r = 0; r < 4; ++r) {
        float rv = rp[r];
        rv += __shfl_xor(rv, 1, 64); rv += __shfl_xor(rv, 2, 64);
        rv += __shfl_xor(rv, 4, 64); rv += __shfl_xor(rv, 8, 64);
        if (l16 == 0) atomicAdd(S + rbase + r, rv);
      }
      er |= __shfl_xor(er, 1, 64); er |= __shfl_xor(er, 2, 64);
      er |= __shfl_xor(er, 4, 64); er |= __shfl_xor(er, 8, 64);
      if (l16 == 0 && er) {
#pragma unroll
        for (int r = 0; r < 4; ++r)
          if ((er >> r) & 1) atomicOr(e + rbase + r, 1);
      }
    } else {
      float rn[4] = {0.f, 0.f, 0.f, 0.f};
#pragma unroll
      for (int j = 0; j < 4; ++j) {
        const f32x4 v = acc[i][j];
        const int c2 = n0 - 2048 + wn * 64 + j * 16 + l16;
        const float bv = bias[c2];
#pragma unroll
        for (int r = 0; r < 4; ++r) {
          const float hv = 1.0f / (1.0f + __expf(-(v[r] + bv)));
          if (IS_L0) {
            Hb[(size_t)(rbase + r) * 2048 + c2] = (bf16)hv;
            rn[r] += hv * hv;
            colp[j] += hv;
          } else {
            Fo[(size_t)(rbase + r) * 1024 + c2] = hv;
          }
        }
      }
      if (IS_L0) {
#pragma unroll
        for (int r = 0; r < 4; ++r) {
          float rv = rn[r];
          rv += __shfl_xor(rv, 1, 64); rv += __shfl_xor(rv, 2, 64);
          rv += __shfl_xor(rv, 4, 64); rv += __shfl_xor(rv, 8, 64);
          if (l16 == 0) atomicAdd(SENhOut + rbase + r, rv);
        }
      }
    }
  }
  if (IS_L0 && !isGram) {
#pragma unroll
    for (int j = 0; j < 4; ++j) {
      float cv = colp[j];
      cv += __shfl_xor(cv, 16, 64);
      cv += __shfl_xor(cv, 32, 64);
      if (lane < 16) atomicAdd(colsumH + (n0 - 2048 + wn * 64 + j * 16 + lane), cv);
    }
  }

  if (IS_L0) return;  // no tail in L0 (moved to L1's tail-0 block)

  // ---- L1 last gemm block: decide1 + lamb1 (fence-free done-counter) ----
  __syncthreads();
  if (tid == 0) s_last = (atomicAdd(cnt, 1) == nblocks - 1);
  __syncthreads();
  if (!s_last) return;
  run_decide_lamb<true>(smemA, e, Dens, S, diagD, lambOut);
}

// --------------------------- small kernels ---------------------------------
// grid 640: b<256 x-rows (convert + SENx atomicExch + 16-bin atomic colsum);
// b<512 W0 convert; else W1 convert. Last block computes stau0 (fence-free).
__global__ void f2b_all(const float* __restrict__ x, const float* __restrict__ W0,
                        const float* __restrict__ W1, bf16* __restrict__ xb,
                        bf16* __restrict__ wb0, bf16* __restrict__ wb1,
                        float* __restrict__ SENx, float* __restrict__ bins,
                        int* __restrict__ cntF, float* __restrict__ scal) {
  const int b = blockIdx.x, tid = threadIdx.x;
  const int wave = tid >> 6, lane = tid & 63;
  __shared__ float ws[8][4];
  __shared__ float red1[256], red2[256];
  __shared__ int s_last;
  if (b < 256) {
    const int r0 = b * 8;
    f32x4 c0 = {0.f, 0.f, 0.f, 0.f}, c1 = {0.f, 0.f, 0.f, 0.f};
    for (int r = 0; r < 8; ++r) {
      const float* src = x + (size_t)(r0 + r) * 2048;
      bf16* dst = xb + (size_t)(r0 + r) * 2048;
      f32x4 v0 = *(const f32x4*)(src + tid * 4);
      f32x4 v1 = *(const f32x4*)(src + 1024 + tid * 4);
      bf16x4 o0, o1;
      o0.x = (bf16)v0.x; o0.y = (bf16)v0.y; o0.z = (bf16)v0.z; o0.w = (bf16)v0.w;
      o1.x = (bf16)v1.x; o1.y = (bf16)v1.y; o1.z = (bf16)v1.z; o1.w = (bf16)v1.w;
      *(bf16x4*)(dst + tid * 4) = o0;
      *(bf16x4*)(dst + 1024 + tid * 4) = o1;
      c0 += v0; c1 += v1;
      float rn = v0.x * v0.x + v0.y * v0.y + v0.z * v0.z + v0.w * v0.w +
                 v1.x * v1.x + v1.y * v1.y + v1.z * v1.z + v1.w * v1.w;
      rn = wave_reduce(rn);
      if (lane == 0) ws[r][wave] = rn;
    }
    __syncthreads();
    if (tid < 8)
      atomicExch(SENx + r0 + tid, ws[tid][0] + ws[tid][1] + ws[tid][2] + ws[tid][3]);
    float* bin = bins + (size_t)(b & 15) * 2048;
    atomicAdd(bin + tid * 4 + 0, c0.x); atomicAdd(bin + tid * 4 + 1, c0.y);
    atomicAdd(bin + tid * 4 + 2, c0.z); atomicAdd(bin + tid * 4 + 3, c0.w);
    atomicAdd(bin + 1024 + tid * 4 + 0, c1.x); atomicAdd(bin + 1024 + tid * 4 + 1, c1.y);
    atomicAdd(bin + 1024 + tid * 4 + 2, c1.z); atomicAdd(bin + 1024 + tid * 4 + 3, c1.w);
  } else if (b < 512) {
    const size_t base = (size_t)(b - 256) * 16384;
    for (int c = tid * 4; c < 16384; c += 1024) {
      f32x4 v = *(const f32x4*)(W0 + base + c);
      bf16x4 o;
      o.x = (bf16)v.x; o.y = (bf16)v.y; o.z = (bf16)v.z; o.w = (bf16)v.w;
      *(bf16x4*)(wb0 + base + c) = o;
    }
  } else {
    const size_t base = (size_t)(b - 512) * 16384;
    for (int c = tid * 4; c < 16384; c += 1024) {
      f32x4 v = *(const f32x4*)(W1 + base + c);
      bf16x4 o;
      o.x = (bf16)v.x; o.y = (bf16)v.y; o.z = (bf16)v.z; o.w = (bf16)v.w;
      *(bf16x4*)(wb1 + base + c) = o;
    }
  }

  // fence-free done-counter finisher: stau0
  __syncthreads();
  if (tid == 0) s_last = (atomicAdd(cntF, 1) == 639);
  __syncthreads();
  if (!s_last) return;
  float ssen = 0.f;
  for (int i = tid; i < 2048; i += 256) ssen += atomicAdd(SENx + i, 0.f);
  float sg2 = 0.f;
  for (int c = tid; c < 2048; c += 256) {
    float cs = 0.f;
#pragma unroll
    for (int p = 0; p < 16; ++p) cs += atomicAdd(bins + (size_t)p * 2048 + c, 0.f);
    const float gm = cs * (1.f / 2048.f);
    sg2 += gm * gm;
  }
  red1[tid] = ssen; red2[tid] = sg2;
  __syncthreads();
  for (int s = 128; s; s >>= 1) {
    if (tid < s) { red1[tid] += red1[tid + s]; red2[tid] += red2[tid + s]; }
    __syncthreads();
  }
  if (tid == 0) {
    const float stau = 0.5f * (red1[0] * (1.f / 2048.f) - red2[0]);
    scal[0] = stau;
    scal[1] = -1.f / stau;
  }
}

// ------------------------------- driver ------------------------------------
extern "C" void kernel_launch(void* const* d_in, const int* in_sizes, int n_in,
                              void* d_out, int out_size, void* d_ws, size_t ws_size,
                              hipStream_t stream) {
  const float* x = (const float*)d_in[0];
  const float* W0 = (const float*)d_in[1];
  const float* b0 = (const float*)d_in[2];
  const float* W1 = (const float*)d_in[3];
  const float* b1 = (const float*)d_in[4];
  float* out = (float*)d_out;

  char* w = (char*)d_ws;
  bf16* xb = (bf16*)(w);                    // 8 MB  [L0 rows 0..2047]
  bf16* wb0 = (bf16*)(w + 8 * MBYTE);       // 8 MB  [L0 rows 2048..4095]
  bf16* hb = (bf16*)(w + 16 * MBYTE);       // 8 MB  [L1 rows 0..2047]
  bf16* wb1 = (bf16*)(w + 24 * MBYTE);      // 4 MB  [L1 rows 2048..3071]
  float* Dens0 = (float*)(w + 28 * MBYTE);  // 16 MB (L0 densities)
  float* Dens1 = (float*)(w);               // 16 MB (L1; overwrites dead xb+wb0)
  float* SENx = (float*)(w + 44 * MBYTE);   // 2048 (atomicExch; no zero needed)
  float* scal = SENx + 2048;                // 16: [0,1]=stau0,-1/stau0
  // ---- zeroed accumulator region (one memset node) ----
  float* zre = scal + 16;
  float* bins = zre;                        // 16*2048 colsum bins
  float* SENh = bins + 16 * 2048;           // 2048
  float* colsumH = SENh + 2048;             // 2048
  float* S0 = colsumH + 2048;               // 2048
  float* S1 = S0 + 2048;                    // 2048
  float* diagD0 = S1 + 2048;                // 2048
  float* diagD1 = diagD0 + 2048;            // 2048
  int* e0 = (int*)(diagD1 + 2048);          // 2048
  int* e1 = e0 + 2048;                      // 2048
  int* cntF = e1 + 2048;
  int* cnt1 = cntF + 1;
  int* flagN = cnt1 + 1;                    // ready flag; value = ninv1
  const size_t zwords = 16 * 2048 + 8 * 2048 + 16;

  float* lamb0 = out + (size_t)2048 * 1024;
  float* lamb1 = lamb0 + 2048;

  hipMemsetAsync(zre, 0, zwords * 4, stream);
  f2b_all<<<640, 256, 0, stream>>>(x, W0, W1, xb, wb0, wb1, SENx, bins, cntF, scal);
  gemm_fused<true><<<dim3(32, 8), 512, 0, stream>>>(
      xb, Dens0, hb, nullptr, b0, SENx, scal + 1, S0, e0, SENh, colsumH,
      diagD0, nullptr, 0, nullptr,
      nullptr, nullptr, nullptr, nullptr, nullptr, nullptr, nullptr, nullptr);
  gemm_fused<false><<<dim3(25, 8), 512, 0, stream>>>(
      hb, Dens1, nullptr, out, b1, SENh, nullptr, S1, e1, nullptr, nullptr,
      diagD1, cnt1, 192, lamb1,
      flagN, SENh, colsumH, e0, S0, diagD0, Dens0, lamb0);
}

// Round 4
// 187.901 us; speedup vs baseline: 1.0472x; 1.0472x over previous
//
#include <hip/hip_runtime.h>
#include <cstdint>
#include <cstddef>

// ---------------------------------------------------------------------------
// SOMFNN forward, 4 dispatches:
//   0. memset    : zero the atomic-accumulator region (~196 KB)
//   1. f2b_all   : convert x/W0/W1 to bf16; SENx + colsum bins; last block
//                  (fence-free done-counter) computes stau0
//   2. gemm L0   : fused Gram(dens,S0,e0,diag0)+sigmoid(hb,SENh,colsumH).
//   3. gemm L1   : 192 gemm blocks (Gram+sigmoid->out) + ONE tail-0 block
//                  (raw bx==24,by==0) computing stau1 then decide0+lamb0;
//                  last gemm block (done-counter) runs decide1+lamb1.
// R13: R12 showed the read path is CONCURRENCY-limited (staging BW fell
// 7.7->5.6 TB/s exactly with in-flight bytes/CU 96->48KB; time constant).
// __syncthreads drains vmcnt(0) so prefetch depth was capped at 1 with a
// one-COMPUTE overlap window. Now: TRIPLE-buffered 48KB tiles (144KB LDS),
// raw s_barrier + counted `s_waitcnt vmcnt(6)` (T4): each wave keeps 12
// loads (2 stages) in flight across barriers; a stage has 2 compute
// phases to complete. Phase = {WAIT(6); BAR; STAGE(buf[s+2]); COMPUTE(
// buf[s])}. STAGE placed AFTER the barrier following its target buffer's
// last read (no WAR race); per-wave vmcnt + barrier => buffer complete
// before any wave reads it (m201 pattern). 30 phases unrolled x3 with
// static buffer names (no runtime indexing -- R10 alias lesson) + 2 tail
// phases (vmcnt 6, then 0).
// Buffer rotation: Dens1 overwrites the dead xb+wb0 region (w+0) so Dens0
// (w+28MB) stays intact for the concurrent decide0.
// Coherence: same-dispatch cross-block data only via device-scope atomics
// (fence-free done-counter: __syncthreads drains vmcnt(0) first); plain
// Dens reads only cross-dispatch or behind the straggler fence.
// Semantics (exact vs reference): stau=base/2 scalar (SENc==cn2); prototypes
// never updated => distances from Gram; e_i=0 => definitively NEW;
// stragglers resolved sequentially (T=0 for this data); lamb =
// dens(n,assigned)/(S[n] - reassigned densities).
// ---------------------------------------------------------------------------

#define DELTA_F 0.13533528323661270f  // float(exp(-2))
#define MBYTE (1u << 20)

typedef __bf16 bf16;
typedef bf16 bf16x8 __attribute__((ext_vector_type(8)));
typedef bf16 bf16x4 __attribute__((ext_vector_type(4)));
typedef float f32x4 __attribute__((ext_vector_type(4)));

typedef __attribute__((address_space(1))) void as1_void;
typedef __attribute__((address_space(3))) void as3_void;

__device__ __forceinline__ void gload16(const bf16* g, bf16* l) {
  __builtin_amdgcn_global_load_lds((as1_void*)g, (as3_void*)l, 16, 0, 0);
}

__device__ __forceinline__ float wave_reduce(float s) {
  for (int o = 32; o > 0; o >>= 1) s += __shfl_down(s, o, 64);
  return s;
}

// ---- shared decide+lamb tail. SAME=true: data written by THIS dispatch
// (atomic reads; fence only on straggler path). SAME=false: previous
// dispatch (plain reads). smem needs >= 24584 bytes. ----
template <bool SAME>
__device__ void run_decide_lamb(char* smem, int* e, float* Dens, float* S,
                                float* diagD, float* lambOut) {
  char* s_flag = smem;                    // 2048
  short* s_as = (short*)(smem + 2048);    // 4096
  short* s_list = (short*)(smem + 6144);  // 4096
  short* s_re = (short*)(smem + 10240);   // 4096
  int* scan_ = (int*)(smem + 14336);      // 2048
  float* rbest = (float*)(smem + 16384);  // 2048
  int* rbj = (int*)(smem + 18432);        // 2048
  int* sT = (int*)(smem + 24576);
  int* sReN = (int*)(smem + 24580);
  const int tid = threadIdx.x;
  int cntl = 0;
#pragma unroll
  for (int k = 0; k < 4; ++k) {
    const int i = tid * 4 + k;
    const int ei = SAME ? atomicOr(e + i, 0) : e[i];
    s_flag[i] = (ei == 0);
    if (ei == 0) s_as[i] = (short)i;
    cntl += (ei != 0);
  }
  scan_[tid] = cntl;
  if (tid == 0) sReN[0] = 0;
  __syncthreads();
  for (int off = 1; off < 512; off <<= 1) {
    const int v = scan_[tid];
    const int add = (tid >= off) ? scan_[tid - off] : 0;
    __syncthreads();
    scan_[tid] = v + add;
    __syncthreads();
  }
  int pos = scan_[tid] - cntl;
#pragma unroll
  for (int k = 0; k < 4; ++k) {
    const int i = tid * 4 + k;
    if (!s_flag[i]) s_list[pos++] = (short)i;
  }
  if (tid == 511) sT[0] = scan_[511];
  __syncthreads();
  const int T = sT[0];
  if (SAME && T > 0) __threadfence();  // straggler path only (rare)
  for (int t = 0; t < T; ++t) {
    const int i = s_list[t];
    const float* di = Dens + (size_t)i * 2048;
    float best = -1.0f;
    int bestj = 0x7fffffff;
    for (int j = tid; j < i; j += 512) {
      if (s_flag[j]) {
        const float d = di[j];
        if (d > best || (d == best && j < bestj)) { best = d; bestj = j; }
      }
    }
    rbest[tid] = best; rbj[tid] = bestj;
    __syncthreads();
    if (tid == 0) {
      float b = -1.0f;
      int bj = 0x7fffffff;
      for (int k = 0; k < 512; ++k)
        if (rbest[k] > b || (rbest[k] == b && rbj[k] < bj)) { b = rbest[k]; bj = rbj[k]; }
      if (b < DELTA_F) { s_flag[i] = 1; s_as[i] = (short)i; }
      else { s_as[i] = (short)bj; s_re[sReN[0]++] = (short)i; }
    }
    __syncthreads();
  }
  const int reN = sReN[0];
#pragma unroll
  for (int k = 0; k < 4; ++k) {
    const int n = k * 512 + tid;
    const int aa = s_as[n];
    const float num = (aa == n)
        ? (SAME ? atomicAdd(diagD + n, 0.f) : diagD[n])
        : Dens[(size_t)n * 2048 + aa];
    float denom = SAME ? atomicAdd(S + n, 0.f) : S[n];
    for (int t = 0; t < reN; ++t) denom -= Dens[(size_t)n * 2048 + s_re[t]];
    lambOut[n] = num / denom;
  }
}

// ------------------------------- GEMM --------------------------------------
// C[2048, *] = A[2048,2048] * Bcat^T, 256x128 tiles, 8 waves = 4m x 2n,
// BK=64, XOR-swizzled LDS (swizzle on global source address).
// 2-ahead prefetch: THREE distinct 48KB __shared__ buffers, counted
// vmcnt(6) + raw s_barrier, one barrier per K-step.
template <bool IS_L0>
__global__ __launch_bounds__(512, 2) void gemm_fused(
    const bf16* __restrict__ A, float* __restrict__ Dens,
    bf16* __restrict__ Hb, float* __restrict__ Fo,
    const float* __restrict__ bias, const float* __restrict__ SENin,
    const float* __restrict__ ninv_p, float* __restrict__ S,
    int* __restrict__ e, float* __restrict__ SENhOut,
    float* __restrict__ colsumH, float* __restrict__ diagD,
    int* __restrict__ cnt, int nblocks, float* __restrict__ lambOut,
    // L1-only (concurrent layer-0 tail):
    int* __restrict__ flagN, const float* __restrict__ SENh_r,
    const float* __restrict__ colsumH_r, int* __restrict__ e0,
    float* __restrict__ S0, float* __restrict__ diag0,
    float* __restrict__ Dens0, float* __restrict__ lamb0) {
  __shared__ __align__(16) char smemA[49152];
  __shared__ __align__(16) char smemB[49152];
  __shared__ __align__(16) char smemC[49152];
  __shared__ int s_last;
  const int tid = threadIdx.x;

  // ---------------- L1 tail-0 block: stau1 + decide0 + lamb0 ---------------
  // (raw blockIdx: specials excluded from the swizzle domain)
  if (!IS_L0 && blockIdx.x == 24) {
    if (blockIdx.y != 0) return;
    float* r1 = (float*)(smemA + 20480);
    float* r2 = (float*)(smemA + 22528);
    float ssen = 0.f, sg2 = 0.f;
    for (int i = tid; i < 2048; i += 512) ssen += SENh_r[i];
    for (int c = tid; c < 2048; c += 512) {
      const float gm = colsumH_r[c] * (1.f / 2048.f);
      sg2 += gm * gm;
    }
    r1[tid] = ssen; r2[tid] = sg2;
    __syncthreads();
    for (int s = 256; s; s >>= 1) {
      if (tid < s) { r1[tid] += r1[tid + s]; r2[tid] += r2[tid + s]; }
      __syncthreads();
    }
    if (tid == 0) {
      const float stau = 0.5f * (r1[0] * (1.f / 2048.f) - r2[0]);
      atomicExch(flagN, __float_as_int(-1.f / stau));  // value IS ninv1
    }
    __syncthreads();
    run_decide_lamb<false>(smemA, e0, Dens0, S0, diag0, lamb0);
    return;
  }

  // ---- XCD-chunked tile mapping: by' = lid&7 (one m-panel per XCD) ----
  int bx, by;
  if (IS_L0) {
    const int lid = blockIdx.x + (blockIdx.y << 5);  // grid (32,8)
    by = lid & 7; bx = lid >> 3;                     // bx 0..31
  } else {
    const int lid = blockIdx.x + blockIdx.y * 25;    // grid (25,8)
    const int xcd = lid & 7, j = lid >> 3;           // j 0..24
    by = xcd; bx = j - (j > 3 * (xcd + 1));          // skip special slot
  }
  const int m0 = by * 256, n0 = bx * 128;

  const int wave = tid >> 6, lane = tid & 63;
  const int quad = lane >> 4, l16 = lane & 15;
  const int wm = wave >> 1, wn = wave & 1;           // 4m x 2n
  const bool isGram = (n0 < 2048);
  const int sr8 = lane >> 3, slot = lane & 7;
  const int gk = (slot ^ sr8) * 8;  // swizzled global k-element offset
  const bf16* aSrc = A + (size_t)(m0 + wave * 32 + sr8) * 2048 + gk;
  const bf16* bSrc = A + (size_t)(n0 + wave * 16 + sr8) * 2048 + gk;
  char* const aDstA = smemA + wave * 4096;
  char* const bDstA = smemA + 32768 + wave * 2048;
  char* const aDstB = smemB + wave * 4096;
  char* const bDstB = smemB + 32768 + wave * 2048;
  char* const aDstC = smemC + wave * 4096;
  char* const bDstC = smemC + 32768 + wave * 2048;
  const int aB = (wm * 64 + l16) * 128;
  const int bB = 32768 + (wn * 64 + l16) * 128;

#define STAGE(aD, bD, k)                                    \
  do {                                                      \
    gload16(aSrc + (k), (bf16*)(aD));                       \
    gload16(aSrc + 8 * 2048 + (k), (bf16*)((aD) + 1024));   \
    gload16(aSrc + 16 * 2048 + (k), (bf16*)((aD) + 2048));  \
    gload16(aSrc + 24 * 2048 + (k), (bf16*)((aD) + 3072));  \
    gload16(bSrc + (k), (bf16*)(bD));                       \
    gload16(bSrc + 8 * 2048 + (k), (bf16*)((bD) + 1024));   \
  } while (0)

#define COMPUTE(sm)                                                          \
  do {                                                                       \
    _Pragma("unroll") for (int ks = 0; ks < 2; ++ks) {                       \
      bf16x8 af[4], bfr[4];                                                  \
      const int sw = ((ks * 4 + quad) ^ (l16 & 7)) * 16;                     \
      _Pragma("unroll") for (int i = 0; i < 4; ++i)                          \
          af[i] = *(const bf16x8*)((sm) + aB + i * 2048 + sw);               \
      _Pragma("unroll") for (int j = 0; j < 4; ++j)                          \
          bfr[j] = *(const bf16x8*)((sm) + bB + j * 2048 + sw);              \
      _Pragma("unroll") for (int i = 0; i < 4; ++i)                          \
          _Pragma("unroll") for (int j = 0; j < 4; ++j) acc[i][j] =          \
              __builtin_amdgcn_mfma_f32_16x16x32_bf16(af[i], bfr[j],         \
                                                      acc[i][j], 0, 0, 0);   \
    }                                                                        \
  } while (0)

// counted-vmcnt barrier: own stage done + all waves past => buffer ready.
// sched_barrier(0) fences both sides of s_barrier (rule #18 insurance).
#define WBAR(n)                                                  \
  do {                                                           \
    asm volatile("s_waitcnt vmcnt(" #n ")" ::: "memory");        \
    __builtin_amdgcn_sched_barrier(0);                           \
    __builtin_amdgcn_s_barrier();                                \
    __builtin_amdgcn_sched_barrier(0);                           \
  } while (0)

  f32x4 acc[4][4] = {};
  STAGE(aDstA, bDstA, 0);    // prologue: steps 0,1 into A,B
  STAGE(aDstB, bDstB, 64);
  for (int k0 = 0; k0 < 1920; k0 += 192) {  // phases 0..29, unrolled x3
    WBAR(6); STAGE(aDstC, bDstC, k0 + 128); COMPUTE(smemA);
    WBAR(6); STAGE(aDstA, bDstA, k0 + 192); COMPUTE(smemB);
    WBAR(6); STAGE(aDstB, bDstB, k0 + 256); COMPUTE(smemC);
  }
  WBAR(6); COMPUTE(smemA);   // phase 30: k=1920 (staged into A)
  WBAR(0); COMPUTE(smemB);   // phase 31: k=1984 (staged into B)
#undef STAGE
#undef COMPUTE
#undef WBAR

  // ninv: L0 = plain read (prev dispatch); L1 = spin on flag (value = ninv1,
  // published ~3us into this dispatch -- epilogue is far later, 0 spins).
  float ninv = 0.f;
  if (isGram) {
    if (IS_L0) ninv = ninv_p[0];
    else {
      int fi;
      while ((fi = atomicOr(flagN, 0)) == 0) {}
      ninv = __int_as_float(fi);
    }
  }

  // epilogue: no kg merge -- every wave writes its own 64x64 sub-tile
  float colp[4] = {0.f, 0.f, 0.f, 0.f};
#pragma unroll
  for (int i = 0; i < 4; ++i) {
    const int rbase = m0 + wm * 64 + i * 16 + quad * 4;
    if (isGram) {
      const f32x4 si4 = *(const f32x4*)(SENin + rbase);
      float rp[4] = {0.f, 0.f, 0.f, 0.f};
      int er = 0;
#pragma unroll
      for (int j = 0; j < 4; ++j) {
        const f32x4 v = acc[i][j];
        const int col = n0 + wn * 64 + j * 16 + l16;
        const float sj = SENin[col];
#pragma unroll
        for (int r = 0; r < 4; ++r) {
          const float dens = __expf((si4[r] + sj - 2.0f * v[r]) * ninv);
          Dens[(size_t)(rbase + r) * 2048 + col] = dens;
          rp[r] += dens;
          if (col < rbase + r && dens >= DELTA_F) er |= (1 << r);
          if (col == rbase + r) atomicExch(diagD + col, dens);
        }
      }
#pragma unroll
      for (int r = 0; r < 4; ++r) {
        float rv = rp[r];
        rv += __shfl_xor(rv, 1, 64); rv += __shfl_xor(rv, 2, 64);
        rv += __shfl_xor(rv, 4, 64); rv += __shfl_xor(rv, 8, 64);
        if (l16 == 0) atomicAdd(S + rbase + r, rv);
      }
      er |= __shfl_xor(er, 1, 64); er |= __shfl_xor(er, 2, 64);
      er |= __shfl_xor(er, 4, 64); er |= __shfl_xor(er, 8, 64);
      if (l16 == 0 && er) {
#pragma unroll
        for (int r = 0; r < 4; ++r)
          if ((er >> r) & 1) atomicOr(e + rbase + r, 1);
      }
    } else {
      float rn[4] = {0.f, 0.f, 0.f, 0.f};
#pragma unroll
      for (int j = 0; j < 4; ++j) {
        const f32x4 v = acc[i][j];
        const int c2 = n0 - 2048 + wn * 64 + j * 16 + l16;
        const float bv = bias[c2];
#pragma unroll
        for (int r = 0; r < 4; ++r) {
          const float hv = 1.0f / (1.0f + __expf(-(v[r] + bv)));
          if (IS_L0) {
            Hb[(size_t)(rbase + r) * 2048 + c2] = (bf16)hv;
            rn[r] += hv * hv;
            colp[j] += hv;
          } else {
            Fo[(size_t)(rbase + r) * 1024 + c2] = hv;
          }
        }
      }
      if (IS_L0) {
#pragma unroll
        for (int r = 0; r < 4; ++r) {
          float rv = rn[r];
          rv += __shfl_xor(rv, 1, 64); rv += __shfl_xor(rv, 2, 64);
          rv += __shfl_xor(rv, 4, 64); rv += __shfl_xor(rv, 8, 64);
          if (l16 == 0) atomicAdd(SENhOut + rbase + r, rv);
        }
      }
    }
  }
  if (IS_L0 && !isGram) {
#pragma unroll
    for (int j = 0; j < 4; ++j) {
      float cv = colp[j];
      cv += __shfl_xor(cv, 16, 64);
      cv += __shfl_xor(cv, 32, 64);
      if (lane < 16) atomicAdd(colsumH + (n0 - 2048 + wn * 64 + j * 16 + lane), cv);
    }
  }

  if (IS_L0) return;  // no tail in L0 (moved to L1's tail-0 block)

  // ---- L1 last gemm block: decide1 + lamb1 (fence-free done-counter) ----
  __syncthreads();
  if (tid == 0) s_last = (atomicAdd(cnt, 1) == nblocks - 1);
  __syncthreads();
  if (!s_last) return;
  run_decide_lamb<true>(smemA, e, Dens, S, diagD, lambOut);
}

// --------------------------- small kernels ---------------------------------
// grid 640: b<256 x-rows (convert + SENx atomicExch + 16-bin atomic colsum);
// b<512 W0 convert; else W1 convert. Last block computes stau0 (fence-free).
__global__ void f2b_all(const float* __restrict__ x, const float* __restrict__ W0,
                        const float* __restrict__ W1, bf16* __restrict__ xb,
                        bf16* __restrict__ wb0, bf16* __restrict__ wb1,
                        float* __restrict__ SENx, float* __restrict__ bins,
                        int* __restrict__ cntF, float* __restrict__ scal) {
  const int b = blockIdx.x, tid = threadIdx.x;
  const int wave = tid >> 6, lane = tid & 63;
  __shared__ float ws[8][4];
  __shared__ float red1[256], red2[256];
  __shared__ int s_last;
  if (b < 256) {
    const int r0 = b * 8;
    f32x4 c0 = {0.f, 0.f, 0.f, 0.f}, c1 = {0.f, 0.f, 0.f, 0.f};
    for (int r = 0; r < 8; ++r) {
      const float* src = x + (size_t)(r0 + r) * 2048;
      bf16* dst = xb + (size_t)(r0 + r) * 2048;
      f32x4 v0 = *(const f32x4*)(src + tid * 4);
      f32x4 v1 = *(const f32x4*)(src + 1024 + tid * 4);
      bf16x4 o0, o1;
      o0.x = (bf16)v0.x; o0.y = (bf16)v0.y; o0.z = (bf16)v0.z; o0.w = (bf16)v0.w;
      o1.x = (bf16)v1.x; o1.y = (bf16)v1.y; o1.z = (bf16)v1.z; o1.w = (bf16)v1.w;
      *(bf16x4*)(dst + tid * 4) = o0;
      *(bf16x4*)(dst + 1024 + tid * 4) = o1;
      c0 += v0; c1 += v1;
      float rn = v0.x * v0.x + v0.y * v0.y + v0.z * v0.z + v0.w * v0.w +
                 v1.x * v1.x + v1.y * v1.y + v1.z * v1.z + v1.w * v1.w;
      rn = wave_reduce(rn);
      if (lane == 0) ws[r][wave] = rn;
    }
    __syncthreads();
    if (tid < 8)
      atomicExch(SENx + r0 + tid, ws[tid][0] + ws[tid][1] + ws[tid][2] + ws[tid][3]);
    float* bin = bins + (size_t)(b & 15) * 2048;
    atomicAdd(bin + tid * 4 + 0, c0.x); atomicAdd(bin + tid * 4 + 1, c0.y);
    atomicAdd(bin + tid * 4 + 2, c0.z); atomicAdd(bin + tid * 4 + 3, c0.w);
    atomicAdd(bin + 1024 + tid * 4 + 0, c1.x); atomicAdd(bin + 1024 + tid * 4 + 1, c1.y);
    atomicAdd(bin + 1024 + tid * 4 + 2, c1.z); atomicAdd(bin + 1024 + tid * 4 + 3, c1.w);
  } else if (b < 512) {
    const size_t base = (size_t)(b - 256) * 16384;
    for (int c = tid * 4; c < 16384; c += 1024) {
      f32x4 v = *(const f32x4*)(W0 + base + c);
      bf16x4 o;
      o.x = (bf16)v.x; o.y = (bf16)v.y; o.z = (bf16)v.z; o.w = (bf16)v.w;
      *(bf16x4*)(wb0 + base + c) = o;
    }
  } else {
    const size_t base = (size_t)(b - 512) * 16384;
    for (int c = tid * 4; c < 16384; c += 1024) {
      f32x4 v = *(const f32x4*)(W1 + base + c);
      bf16x4 o;
      o.x = (bf16)v.x; o.y = (bf16)v.y; o.z = (bf16)v.z; o.w = (bf16)v.w;
      *(bf16x4*)(wb1 + base + c) = o;
    }
  }

  // fence-free done-counter finisher: stau0
  __syncthreads();
  if (tid == 0) s_last = (atomicAdd(cntF, 1) == 639);
  __syncthreads();
  if (!s_last) return;
  float ssen = 0.f;
  for (int i = tid; i < 2048; i += 256) ssen += atomicAdd(SENx + i, 0.f);
  float sg2 = 0.f;
  for (int c = tid; c < 2048; c += 256) {
    float cs = 0.f;
#pragma unroll
    for (int p = 0; p < 16; ++p) cs += atomicAdd(bins + (size_t)p * 2048 + c, 0.f);
    const float gm = cs * (1.f / 2048.f);
    sg2 += gm * gm;
  }
  red1[tid] = ssen; red2[tid] = sg2;
  __syncthreads();
  for (int s = 128; s; s >>= 1) {
    if (tid < s) { red1[tid] += red1[tid + s]; red2[tid] += red2[tid + s]; }
    __syncthreads();
  }
  if (tid == 0) {
    const float stau = 0.5f * (red1[0] * (1.f / 2048.f) - red2[0]);
    scal[0] = stau;
    scal[1] = -1.f / stau;
  }
}

// ------------------------------- driver ------------------------------------
extern "C" void kernel_launch(void* const* d_in, const int* in_sizes, int n_in,
                              void* d_out, int out_size, void* d_ws, size_t ws_size,
                              hipStream_t stream) {
  const float* x = (const float*)d_in[0];
  const float* W0 = (const float*)d_in[1];
  const float* b0 = (const float*)d_in[2];
  const float* W1 = (const float*)d_in[3];
  const float* b1 = (const float*)d_in[4];
  float* out = (float*)d_out;

  char* w = (char*)d_ws;
  bf16* xb = (bf16*)(w);                    // 8 MB  [L0 rows 0..2047]
  bf16* wb0 = (bf16*)(w + 8 * MBYTE);       // 8 MB  [L0 rows 2048..4095]
  bf16* hb = (bf16*)(w + 16 * MBYTE);       // 8 MB  [L1 rows 0..2047]
  bf16* wb1 = (bf16*)(w + 24 * MBYTE);      // 4 MB  [L1 rows 2048..3071]
  float* Dens0 = (float*)(w + 28 * MBYTE);  // 16 MB (L0 densities)
  float* Dens1 = (float*)(w);               // 16 MB (L1; overwrites dead xb+wb0)
  float* SENx = (float*)(w + 44 * MBYTE);   // 2048 (atomicExch; no zero needed)
  float* scal = SENx + 2048;                // 16: [0,1]=stau0,-1/stau0
  // ---- zeroed accumulator region (one memset node) ----
  float* zre = scal + 16;
  float* bins = zre;                        // 16*2048 colsum bins
  float* SENh = bins + 16 * 2048;           // 2048
  float* colsumH = SENh + 2048;             // 2048
  float* S0 = colsumH + 2048;               // 2048
  float* S1 = S0 + 2048;                    // 2048
  float* diagD0 = S1 + 2048;                // 2048
  float* diagD1 = diagD0 + 2048;            // 2048
  int* e0 = (int*)(diagD1 + 2048);          // 2048
  int* e1 = e0 + 2048;                      // 2048
  int* cntF = e1 + 2048;
  int* cnt1 = cntF + 1;
  int* flagN = cnt1 + 1;                    // ready flag; value = ninv1
  const size_t zwords = 16 * 2048 + 8 * 2048 + 16;

  float* lamb0 = out + (size_t)2048 * 1024;
  float* lamb1 = lamb0 + 2048;

  hipMemsetAsync(zre, 0, zwords * 4, stream);
  f2b_all<<<640, 256, 0, stream>>>(x, W0, W1, xb, wb0, wb1, SENx, bins, cntF, scal);
  gemm_fused<true><<<dim3(32, 8), 512, 0, stream>>>(
      xb, Dens0, hb, nullptr, b0, SENx, scal + 1, S0, e0, SENh, colsumH,
      diagD0, nullptr, 0, nullptr,
      nullptr, nullptr, nullptr, nullptr, nullptr, nullptr, nullptr, nullptr);
  gemm_fused<false><<<dim3(25, 8), 512, 0, stream>>>(
      hb, Dens1, nullptr, out, b1, SENh, nullptr, S1, e1, nullptr, nullptr,
      diagD1, cnt1, 192, lamb1,
      flagN, SENh, colsumH, e0, S0, diagD0, Dens0, lamb0);
}